// Round 9
// baseline (594.990 us; speedup 1.0000x reference)
//
#include <hip/hip_runtime.h>
#include <stdint.h>

#define N_COLS   32768
#define N_ROWS   256
#define N_TASKS  512          // 256 rows x {predictions, targets}
#define B1       2048         // level-1 bins (top 11 bits of key)
#define SHIFT1   21
#define SHIFT2L  13           // k_large sub-bin tag: key bits [20:13] (256 bins)
#define B2L      256
#define SMALL_THR 64u
#define CAP_W    2048         // per-wave LDS bucket capacity (max expected ~1900)
#define HCOLS    8            // cursor columns per bin: 2 half-blocks x 4 wave-reps
#define HTOT     (B1 * HCOLS) // 16384 u32 per task

typedef unsigned long long ull;

// order-preserving float->uint32 key
__device__ __forceinline__ uint32_t fkey(float x) {
    uint32_t u = __float_as_uint(x);
    return u ^ ((uint32_t)((int32_t)u >> 31) | 0x80000000u);
}

__device__ __forceinline__ const float* task_src(int t, const float* P, const float* Tg) {
    return (t < N_ROWS ? P : Tg) + (size_t)(t & (N_ROWS - 1)) * N_COLS;
}

// ---- K1: per-task histogram, 2 blocks/task, 4 wave-replica columns each ----
// Element->column mapping: block half = bid&1 covers j4 in [half*4096,(half+1)*4096),
// thread tid -> rep (tid>>6)&3. MUST match k_scatter exactly.
__global__ void __launch_bounds__(512) k_hist(const float* P, const float* Tg, uint32_t* hist) {
    int t = blockIdx.x >> 1, half = blockIdx.x & 1;
    const float* src = task_src(t, P, Tg);
    __shared__ uint32_t h[B1 * 4];
    for (int i = threadIdx.x; i < B1 * 4; i += 512) h[i] = 0;
    __syncthreads();
    int rep = (threadIdx.x >> 6) & 3;
    for (int j4 = half * 4096 + threadIdx.x; j4 < (half + 1) * 4096; j4 += 512) {
        float4 v = ((const float4*)src)[j4];
        atomicAdd(&h[((fkey(v.x) >> SHIFT1) << 2) + rep], 1u);
        atomicAdd(&h[((fkey(v.y) >> SHIFT1) << 2) + rep], 1u);
        atomicAdd(&h[((fkey(v.z) >> SHIFT1) << 2) + rep], 1u);
        atomicAdd(&h[((fkey(v.w) >> SHIFT1) << 2) + rep], 1u);
    }
    __syncthreads();
    uint32_t* o = hist + (size_t)t * HTOT + (size_t)half * (B1 * 4);
    for (int i = threadIdx.x; i < B1 * 4; i += 512) o[i] = h[i];
}

// ---- K2: per-task exclusive prefix over 8 columns -> cursor starts + work lists ----
__global__ void __launch_bounds__(256) k_scan(uint32_t* hist, uint32_t* cnts,
                                              ull* list, ull* slist) {
    int t = blockIdx.x;
    uint32_t* hb = hist + (size_t)t * HTOT;
    __shared__ uint32_t stmp[256];
    uint32_t run = 0;
    for (int c = 0; c < B1 / 256; ++c) {
        int bin = c * 256 + threadIdx.x;
        uint4 ha = *(uint4*)(hb + 4 * bin);          // half0, reps 0..3
        uint4 hb4 = *(uint4*)(hb + 8192 + 4 * bin);  // half1, reps 0..3
        uint32_t v = ha.x + ha.y + ha.z + ha.w + hb4.x + hb4.y + hb4.z + hb4.w;
        stmp[threadIdx.x] = v;
        __syncthreads();
        for (int off = 1; off < 256; off <<= 1) {
            uint32_t x = (threadIdx.x >= (unsigned)off) ? stmp[threadIdx.x - off] : 0u;
            __syncthreads();
            stmp[threadIdx.x] += x;
            __syncthreads();
        }
        uint32_t incl = stmp[threadIdx.x];
        uint32_t tot  = stmp[255];
        uint32_t start = run + incl - v;     // task-local exclusive prefix (bucket start)
        if (v > SMALL_THR) {
            uint32_t p = atomicAdd(&cnts[0], 1u);
            list[p] = ((ull)t << 32) | ((ull)start << 16) | v;
        } else if (v) {
            uint32_t p = atomicAdd(&cnts[1], 1u);
            slist[p] = ((ull)t << 32) | ((ull)start << 16) | v;
        }
        uint4 wa, wb;                        // per-column cursor starts, order: h0r0..h0r3,h1r0..h1r3
        wa.x = start;
        wa.y = wa.x + ha.x;  wa.z = wa.y + ha.y;  wa.w = wa.z + ha.z;
        wb.x = wa.w + ha.w;  wb.y = wb.x + hb4.x; wb.z = wb.y + hb4.y; wb.w = wb.z + hb4.z;
        *(uint4*)(hb + 4 * bin) = wa;
        *(uint4*)(hb + 8192 + 4 * bin) = wb;
        run += tot;
        __syncthreads();
    }
}

// ---- K3: counting-sort scatter, 2 blocks/task, LDS cursors, packed 8B stores ----
__global__ void __launch_bounds__(512) k_scatter(const float* P, const float* Tg, const uint32_t* hist,
                                                 ull* rec8) {
    int t = blockIdx.x >> 1, half = blockIdx.x & 1;
    const float* src = task_src(t, P, Tg);
    const uint32_t* h = hist + (size_t)t * HTOT + (size_t)half * (B1 * 4);
    __shared__ uint32_t sc[B1 * 4];
    for (int i = threadIdx.x; i < B1 * 4; i += 512) sc[i] = h[i];
    __syncthreads();
    int rep = (threadIdx.x >> 6) & 3;         // must match k_hist
    size_t base = (size_t)t << 15;
    for (int j4 = half * 4096 + threadIdx.x; j4 < (half + 1) * 4096; j4 += 512) {
        float4 v = ((const float4*)src)[j4];
        float xs[4] = {v.x, v.y, v.z, v.w};
#pragma unroll
        for (int c = 0; c < 4; ++c) {
            uint32_t k = fkey(xs[c]);
            uint32_t pos = atomicAdd(&sc[((k >> SHIFT1) << 2) + rep], 1u);
            rec8[base + pos] = ((ull)k << 32) | (ull)(j4 * 4 + c);
        }
    }
}

// ---- K4: rank large buckets — wave-per-bucket, work-stealing, element-centric D ----
// Per-wave LDS slice 11.25 KB (sk2 8K + sh 1K + sd2 2K + pad); 2-wave blocks -> 22.5 KB
// -> 7 blocks/CU = 14 waves/CU. Dynamic queue (cnts[2], batch 2) kills the size-variance
// tail that capped r8's time-avg occupancy at 29.5%.
__global__ void __launch_bounds__(128) k_large(const ull* rec8, uint16_t* sid,
                                               uint32_t* cnts, const ull* list) {
    __shared__ uint32_t sk2[2][CAP_W];   // 16 KB: packed (keylow13<<15|id), grouped by sub-bin
    __shared__ uint32_t sh[2][B2L];      //  2 KB: sub-bin hist/cursors/ends
    __shared__ uint8_t  sd2[2][CAP_W];   //  4 KB: per-element sub-bin tag
    uint32_t w = threadIdx.x >> 6, lane = threadIdx.x & 63u;
    uint32_t nlist = cnts[0];
    for (;;) {
        uint32_t e0 = 0;
        if (lane == 0) e0 = atomicAdd(&cnts[2], 2u);
        uint32_t ebase = __shfl(e0, 0, 64);
        if (ebase >= nlist) break;
        uint32_t eend = ebase + 2u; if (eend > nlist) eend = nlist;
        for (uint32_t e = ebase; e < eend; ++e) {
            ull ent = list[e];
            uint32_t t     = (uint32_t)(ent >> 32);
            uint32_t start = (uint32_t)(ent >> 16) & 0xFFFFu;
            uint32_t m     = (uint32_t)ent & 0xFFFFu;
            const uint2* src2 = (const uint2*)(rec8 + ((size_t)t << 15) + start);  // .x=id .y=key
            size_t outb = ((size_t)t << 15) + start;
            if (m <= CAP_W) {
                // phase A: zero + sub-histogram on bits [20:13]; paired loads for ILP
                for (uint32_t b = lane; b < B2L; b += 64) sh[w][b] = 0;
                __threadfence_block();
                for (uint32_t i = lane; i < m; i += 128) {
                    uint2 ra = src2[i];
                    uint32_t i2 = i + 64; bool hb = i2 < m;
                    uint2 rb; if (hb) rb = src2[i2];
                    atomicAdd(&sh[w][(ra.y >> SHIFT2L) & 255u], 1u);
                    if (hb) atomicAdd(&sh[w][(rb.y >> SHIFT2L) & 255u], 1u);
                }
                __threadfence_block();
                // phase B: wave-scan of 256 bins (4 bins/lane)
                uint32_t b0 = sh[w][4 * lane], b1 = sh[w][4 * lane + 1];
                uint32_t b2 = sh[w][4 * lane + 2], b3 = sh[w][4 * lane + 3];
                uint32_t s4 = b0 + b1 + b2 + b3;
                uint32_t incl = s4;
#pragma unroll
                for (int off = 1; off < 64; off <<= 1) {
                    uint32_t x = __shfl_up(incl, off, 64);
                    if ((int)lane >= off) incl += x;
                }
                uint32_t excl = incl - s4;
                sh[w][4 * lane]     = excl;
                sh[w][4 * lane + 1] = excl + b0;
                sh[w][4 * lane + 2] = excl + b0 + b1;
                sh[w][4 * lane + 3] = excl + b0 + b1 + b2;
                __threadfence_block();
                // phase C: scatter packed cmp + tag into LDS at sub-bin cursors
                for (uint32_t i = lane; i < m; i += 128) {
                    uint2 ra = src2[i];
                    uint32_t i2 = i + 64; bool hb = i2 < m;
                    uint2 rb; if (hb) rb = src2[i2];
                    uint32_t da = (ra.y >> SHIFT2L) & 255u;
                    uint32_t pa = atomicAdd(&sh[w][da], 1u);
                    sk2[w][pa] = ((ra.y & 0x1FFFu) << 15) | (ra.x & 0x7FFFu);
                    sd2[w][pa] = (uint8_t)da;
                    if (hb) {
                        uint32_t db = (rb.y >> SHIFT2L) & 255u;
                        uint32_t pb = atomicAdd(&sh[w][db], 1u);
                        sk2[w][pb] = ((rb.y & 0x1FFFu) << 15) | (rb.x & 0x7FFFu);
                        sd2[w][pb] = (uint8_t)db;
                    }
                }
                __threadfence_block();
                // phase D: element-centric rank; sh now = inclusive ends.
                // Consecutive p -> coalesced own/tag reads; same-group walks broadcast.
                for (uint32_t p = lane; p < m; p += 64) {
                    uint32_t pi = sk2[w][p];
                    uint32_t d2 = sd2[w][p];
                    uint32_t gs = d2 ? sh[w][d2 - 1] : 0u;
                    uint32_t ge = sh[w][d2];
                    uint32_t cnt = 0;
                    for (uint32_t q = gs; q < ge; ++q) cnt += (sk2[w][q] < pi) ? 1u : 0u;
                    sid[outb + gs + cnt] = (uint16_t)(pi & 0x7FFFu);
                }
                __threadfence_block();   // drain before next entry reuses the slice
            } else { // safety fallback (statistically unreachable): O(m^2) global
                const ull* src = rec8 + ((size_t)t << 15) + start;
                for (uint32_t i = lane; i < m; i += 64) {
                    ull rr = src[i];
                    uint32_t k = (uint32_t)(rr >> 32), id = (uint32_t)(rr & 0xFFFFu);
                    uint32_t cnt = 0;
                    for (uint32_t q = 0; q < m; ++q) {
                        ull rq = src[q];
                        uint32_t kq = (uint32_t)(rq >> 32), iq = (uint32_t)(rq & 0xFFFFu);
                        cnt += (kq < k || (kq == k && iq < id)) ? 1u : 0u;
                    }
                    sid[outb + cnt] = (uint16_t)id;
                }
            }
        }
    }
}

// ---- K5: rank small buckets (1..64) — one wave per entry, batched stealing ----
__global__ void __launch_bounds__(256) k_small(const ull* rec8, uint16_t* sid,
                                               uint32_t* cnts, const ull* slist) {
    uint32_t lane = threadIdx.x & 63u;
    uint32_t nsl  = cnts[1];
    for (;;) {
        uint32_t e0 = 0;
        if (lane == 0) e0 = atomicAdd(&cnts[3], 8u);
        uint32_t ebase = __shfl(e0, 0, 64);
        if (ebase >= nsl) break;
        uint32_t eend = ebase + 8u; if (eend > nsl) eend = nsl;
        for (uint32_t e = ebase; e < eend; ++e) {
            ull ent = slist[e];
            uint32_t t     = (uint32_t)(ent >> 32);
            uint32_t start = (uint32_t)(ent >> 16) & 0xFFFFu;
            uint32_t m     = (uint32_t)ent & 0xFFFFu;
            size_t base = (size_t)t << 15;
            uint32_t id = 0xFFFFFFFFu, k = 0u;
            if (lane < m) {
                ull rr = rec8[base + start + lane];
                k = (uint32_t)(rr >> 32); id = (uint32_t)(rr & 0xFFFFu);
            }
            uint32_t cnt = 0;
            for (uint32_t q = 0; q < m; ++q) {
                uint32_t kq = __shfl(k, (int)q, 64);
                uint32_t iq = __shfl(id, (int)q, 64);
                cnt += (kq < k || (kq == k && iq < id)) ? 1u : 0u;
            }
            if (lane < m) sid[base + start + cnt] = (uint16_t)id;
        }
    }
}

// ---- K6: per-row dot via LDS inverse permutation ----
__global__ void __launch_bounds__(1024) k_dot(const uint16_t* sid, double* rowloss) {
    extern __shared__ uint8_t smem[];
    uint16_t* inv = (uint16_t*)smem;    // 64 KB: inverse perm of targets row
    int r = blockIdx.x, tid = threadIdx.x;
    const uint4* t4 = (const uint4*)(sid + ((size_t)(r + N_ROWS) << 15));
    const uint4* p4 = (const uint4*)(sid + ((size_t)r << 15));
    for (int j8 = tid; j8 < N_COLS / 8; j8 += 1024) {
        uint4 v = t4[j8];
        uint32_t j = (uint32_t)j8 * 8u;
        inv[v.x & 0xFFFFu] = (uint16_t)(j + 0); inv[v.x >> 16] = (uint16_t)(j + 1);
        inv[v.y & 0xFFFFu] = (uint16_t)(j + 2); inv[v.y >> 16] = (uint16_t)(j + 3);
        inv[v.z & 0xFFFFu] = (uint16_t)(j + 4); inv[v.z >> 16] = (uint16_t)(j + 5);
        inv[v.w & 0xFFFFu] = (uint16_t)(j + 6); inv[v.w >> 16] = (uint16_t)(j + 7);
    }
    __syncthreads();
    ull s = 0;
    for (int j8 = tid; j8 < N_COLS / 8; j8 += 1024) {
        uint4 v = p4[j8];
        ull j = (ull)j8 * 8u;
        s += (j + 0) * (ull)inv[v.x & 0xFFFFu];
        s += (j + 1) * (ull)inv[v.x >> 16];
        s += (j + 2) * (ull)inv[v.y & 0xFFFFu];
        s += (j + 3) * (ull)inv[v.y >> 16];
        s += (j + 4) * (ull)inv[v.z & 0xFFFFu];
        s += (j + 5) * (ull)inv[v.z >> 16];
        s += (j + 6) * (ull)inv[v.w & 0xFFFFu];
        s += (j + 7) * (ull)inv[v.w >> 16];
    }
    for (int off = 32; off; off >>= 1) s += __shfl_down(s, off, 64);
    __shared__ ull sws[16];
    int w = tid >> 6, lane = tid & 63;
    if (lane == 0) sws[w] = s;
    __syncthreads();
    if (tid == 0) {
        ull tot = 0;
        for (int i = 0; i < 16; ++i) tot += sws[i];
        double S   = (double)tot;
        double num = S - 32768.0 * 16383.5 * 16383.5;        // S - n*mu^2 (exact)
        double den = 32768.0 * 1073741823.0 / 12.0;          // n(n^2-1)/12
        rowloss[r] = 1.0 - num / (den + 1e-8);
    }
}

// ---- K7: deterministic fixed-order final reduction ----
__global__ void __launch_bounds__(256) k_final(const double* rowloss, float* out) {
    __shared__ double s[256];
    s[threadIdx.x] = rowloss[threadIdx.x];
    __syncthreads();
    for (int off = 128; off; off >>= 1) {
        if ((int)threadIdx.x < off) s[threadIdx.x] += s[threadIdx.x + off];
        __syncthreads();
    }
    if (threadIdx.x == 0) out[0] = (float)(s[0] / 256.0);
}

extern "C" void kernel_launch(void* const* d_in, const int* in_sizes, int n_in,
                              void* d_out, int out_size, void* d_ws, size_t ws_size,
                              hipStream_t stream) {
    const float* P  = (const float*)d_in[0];
    const float* Tg = (const float*)d_in[1];
    float* out = (float*)d_out;
    char* ws = (char*)d_ws;
    const size_t MB = 1024 * 1024;

    // hist (32 MB) is dead after k_scatter; sid (32 MB) aliases it (written strictly later).
    uint32_t* hist = (uint32_t*)(ws);                          // 32 MB (512 x 16384 u32)
    uint16_t* sid  = (uint16_t*)(ws);                          // 32 MB (aliases hist)
    uint32_t* cnts = (uint32_t*)(ws + 32 * MB);                // 16 B (nlist,nslist,steal_l,steal_s)
    ull* list      = (ull*)(ws + 32 * MB + 4096);              // ~2 MB
    ull* slist     = (ull*)(ws + 34 * MB);                     // 6 MB
    double* rowloss = (double*)(ws + 40 * MB);                 // 2 KB
    ull* rec8      = (ull*)(ws + 41 * MB);                     // 128 MB -> total 169 MB (ws >= 189 MB verified r8)

    (void)hipFuncSetAttribute((const void*)k_dot,
                              hipFuncAttributeMaxDynamicSharedMemorySize, 65536);

    hipMemsetAsync(cnts, 0, 16, stream);

    k_hist   <<<N_TASKS * 2, 512, 0, stream>>>(P, Tg, hist);
    k_scan   <<<N_TASKS, 256, 0, stream>>>(hist, cnts, list, slist);
    k_scatter<<<N_TASKS * 2, 512, 0, stream>>>(P, Tg, hist, rec8);
    k_large  <<<1792, 128, 0, stream>>>(rec8, sid, cnts, list);
    k_small  <<<2048, 256, 0, stream>>>(rec8, sid, cnts, slist);
    k_dot    <<<N_ROWS, 1024, 65536, stream>>>(sid, rowloss);
    k_final  <<<1, 256, 0, stream>>>(rowloss, out);
}

// Round 10
// 481.863 us; speedup vs baseline: 1.2348x; 1.2348x over previous
//
#include <hip/hip_runtime.h>
#include <stdint.h>

#define N_COLS   32768
#define N_ROWS   256
#define N_TASKS  512          // 256 rows x {predictions, targets}
#define B1       2048         // level-1 bins (top 11 bits of key)
#define SHIFT1   21
#define B2V      512          // k_large sub-bins: key bits [20:12]
#define SMALL_THR 64u
#define CAP_W    2048         // per-wave LDS bucket capacity (expected max ~1900)
#define HREP     4            // per-wave histogram/cursor replicas (contention split)
#define HTOT     (B1 * HREP)  // 8192 u32 per task

typedef unsigned long long ull;

// order-preserving float->uint32 key
__device__ __forceinline__ uint32_t fkey(float x) {
    uint32_t u = __float_as_uint(x);
    return u ^ ((uint32_t)((int32_t)u >> 31) | 0x80000000u);
}

__device__ __forceinline__ const float* task_src(int t, const float* P, const float* Tg) {
    return (t < N_ROWS ? P : Tg) + (size_t)(t & (N_ROWS - 1)) * N_COLS;
}

// ---- K1: per-task histogram, 4 replicas per bin (round-8 verbatim) ----
// element->replica mapping (512 threads, j4 stride 512, rep=(tid>>6)&3) MUST match k_scatter.
__global__ void __launch_bounds__(512) k_hist(const float* P, const float* Tg, uint32_t* hist) {
    int t = blockIdx.x;
    const float* src = task_src(t, P, Tg);
    __shared__ uint32_t h[HTOT];
    for (int i = threadIdx.x; i < HTOT; i += 512) h[i] = 0;
    __syncthreads();
    int rep = (threadIdx.x >> 6) & 3;
    for (int j4 = threadIdx.x; j4 < N_COLS / 4; j4 += 512) {
        float4 v = ((const float4*)src)[j4];
        atomicAdd(&h[((fkey(v.x) >> SHIFT1) << 2) + rep], 1u);
        atomicAdd(&h[((fkey(v.y) >> SHIFT1) << 2) + rep], 1u);
        atomicAdd(&h[((fkey(v.z) >> SHIFT1) << 2) + rep], 1u);
        atomicAdd(&h[((fkey(v.w) >> SHIFT1) << 2) + rep], 1u);
    }
    __syncthreads();
    uint32_t* o = hist + (size_t)t * HTOT;
    for (int i = threadIdx.x; i < HTOT; i += 512) o[i] = h[i];
}

// ---- K2: per-task exclusive prefix -> per-replica cursors + work lists (round-8 verbatim) ----
__global__ void __launch_bounds__(256) k_scan(uint32_t* hist, uint32_t* cnts,
                                              ull* list, ull* slist) {
    int t = blockIdx.x;
    uint4* h4 = (uint4*)(hist + (size_t)t * HTOT);
    __shared__ uint32_t stmp[256];
    uint32_t run = 0;
    for (int c = 0; c < B1 / 256; ++c) {
        int bin = c * 256 + threadIdx.x;
        uint4 hv = h4[bin];
        uint32_t v = hv.x + hv.y + hv.z + hv.w;
        stmp[threadIdx.x] = v;
        __syncthreads();
        for (int off = 1; off < 256; off <<= 1) {
            uint32_t x = (threadIdx.x >= (unsigned)off) ? stmp[threadIdx.x - off] : 0u;
            __syncthreads();
            stmp[threadIdx.x] += x;
            __syncthreads();
        }
        uint32_t incl = stmp[threadIdx.x];
        uint32_t tot  = stmp[255];
        uint32_t start = run + incl - v;     // task-local exclusive prefix (bucket start)
        if (v > SMALL_THR) {
            uint32_t p = atomicAdd(&cnts[0], 1u);
            list[p] = ((ull)t << 32) | ((ull)start << 16) | v;
        } else if (v) {
            uint32_t p = atomicAdd(&cnts[1], 1u);
            slist[p] = ((ull)t << 32) | ((ull)start << 16) | v;
        }
        uint4 w;                              // per-replica cursor starts
        w.x = start;
        w.y = w.x + hv.x;
        w.z = w.y + hv.y;
        w.w = w.z + hv.z;
        h4[bin] = w;
        run += tot;
        __syncthreads();
    }
}

// ---- K3: counting-sort scatter, LDS cursors, packed 8B stores (round-8 verbatim) ----
__global__ void __launch_bounds__(512) k_scatter(const float* P, const float* Tg, const uint32_t* hist,
                                                 ull* rec8) {
    int t = blockIdx.x;
    const float* src = task_src(t, P, Tg);
    const uint32_t* h = hist + (size_t)t * HTOT;
    __shared__ uint32_t sc[HTOT];
    for (int i = threadIdx.x; i < HTOT; i += 512) sc[i] = h[i];
    __syncthreads();
    int rep = (threadIdx.x >> 6) & 3;         // must match k_hist
    size_t base = (size_t)t << 15;
    for (int j4 = threadIdx.x; j4 < N_COLS / 4; j4 += 512) {
        float4 v = ((const float4*)src)[j4];
        float xs[4] = {v.x, v.y, v.z, v.w};
#pragma unroll
        for (int c = 0; c < 4; ++c) {
            uint32_t k = fkey(xs[c]);
            uint32_t pos = atomicAdd(&sc[((k >> SHIFT1) << 2) + rep], 1u);
            rec8[base + pos] = ((ull)k << 32) | (ull)(j4 * 4 + c);
        }
    }
}

// ---- K4: rank large buckets — round-8 skeleton + reg-staged bucket + 1 entry/wave ----
// Changes vs round 8 (164us, VALU 45%, occ 29.5%): (1) bucket loaded ONCE into rg[32]
// (32 pipelined loads, phase C reads regs, not global); (2) grid 8192 blocks -> 1 entry
// per wave, HW dispatcher load-balances (no stealing atomic — r9 showed it hurts).
__global__ void __launch_bounds__(256) k_large(const ull* rec8, uint16_t* sid,
                                               const uint32_t* cnts, const ull* list) {
    __shared__ uint32_t sk2[4][CAP_W];   // 32 KB: packed cmp values, grouped by sub-bin
    __shared__ uint32_t sh[4][B2V];      //  8 KB: sub-bin hist/cursors/ends
    uint32_t w = threadIdx.x >> 6, lane = threadIdx.x & 63u;
    uint32_t gw = blockIdx.x * 4u + w;
    uint32_t nw = gridDim.x * 4u;
    uint32_t nlist = cnts[0];
    for (uint32_t e = gw; e < nlist; e += nw) {
        ull ent = list[e];
        uint32_t t     = (uint32_t)(ent >> 32);
        uint32_t start = (uint32_t)(ent >> 16) & 0xFFFFu;
        uint32_t m     = (uint32_t)ent & 0xFFFFu;
        const uint2* src2 = (const uint2*)(rec8 + ((size_t)t << 15) + start);  // .x=id, .y=key
        size_t outb = ((size_t)t << 15) + start;
        if (m <= CAP_W) {
            uint2 rg[32];                    // lane's elements: i = lane + 64*j (static idx only)
            // phase A0: zero sub-hist
            for (uint32_t b = lane; b < B2V; b += 64) sh[w][b] = 0;
            __threadfence_block();
            // phase A1: load whole bucket into regs (independent loads pipeline deep)
#pragma unroll
            for (int j = 0; j < 32; ++j) {
                uint32_t i = lane + 64u * (uint32_t)j;
                if (i < m) rg[j] = src2[i];
            }
            // phase A2: sub-histogram on key bits [20:12]
#pragma unroll
            for (int j = 0; j < 32; ++j) {
                uint32_t i = lane + 64u * (uint32_t)j;
                if (i < m) atomicAdd(&sh[w][(rg[j].y >> 12) & (B2V - 1u)], 1u);
            }
            __threadfence_block();
            // phase B: wave-scan of 512 bins (8 bins/lane, shfl inclusive scan)
            uint32_t bb[8]; uint32_t s8 = 0;
#pragma unroll
            for (int j = 0; j < 8; ++j) { bb[j] = sh[w][8 * lane + j]; s8 += bb[j]; }
            uint32_t incl = s8;
#pragma unroll
            for (int off = 1; off < 64; off <<= 1) {
                uint32_t x = __shfl_up(incl, off, 64);
                if ((int)lane >= off) incl += x;
            }
            uint32_t excl = incl - s8;
#pragma unroll
            for (int j = 0; j < 8; ++j) { sh[w][8 * lane + j] = excl; excl += bb[j]; }
            __threadfence_block();
            // phase C: scatter packed cmp from REGS into LDS at sub-bin cursors
#pragma unroll
            for (int j = 0; j < 32; ++j) {
                uint32_t i = lane + 64u * (uint32_t)j;
                if (i < m) {
                    uint32_t pos = atomicAdd(&sh[w][(rg[j].y >> 12) & (B2V - 1u)], 1u);
                    sk2[w][pos] = ((rg[j].y & 0xFFFu) << 15) | (rg[j].x & 0x7FFFu);
                }
            }
            __threadfence_block();
            // phase D: group-centric rank (round-8 form); sh now = inclusive ends
            for (uint32_t d2 = lane; d2 < B2V; d2 += 64) {
                uint32_t gs = d2 ? sh[w][d2 - 1] : 0u;
                uint32_t ge = sh[w][d2];
                for (uint32_t p = gs; p < ge; ++p) {
                    uint32_t pi = sk2[w][p];
                    uint32_t cnt = 0, q = gs;
                    for (; q + 4 <= ge; q += 4) {
                        uint32_t a = sk2[w][q], b = sk2[w][q + 1];
                        uint32_t c = sk2[w][q + 2], d = sk2[w][q + 3];
                        cnt += (a < pi) + (b < pi) + (c < pi) + (d < pi);
                    }
                    for (; q < ge; ++q) cnt += (sk2[w][q] < pi) ? 1u : 0u;
                    sid[outb + gs + cnt] = (uint16_t)(pi & 0x7FFFu);
                }
            }
            __threadfence_block();   // drain before next entry reuses the slice
        } else { // safety fallback (statistically unreachable): O(m^2) global, broadcast reads
            const ull* src = rec8 + ((size_t)t << 15) + start;
            for (uint32_t i = lane; i < m; i += 64) {
                ull rr = src[i];
                uint32_t k = (uint32_t)(rr >> 32), id = (uint32_t)(rr & 0xFFFFu);
                uint32_t cnt = 0;
                for (uint32_t q = 0; q < m; ++q) {
                    ull rq = src[q];
                    uint32_t kq = (uint32_t)(rq >> 32), iq = (uint32_t)(rq & 0xFFFFu);
                    cnt += (kq < k || (kq == k && iq < id)) ? 1u : 0u;
                }
                sid[outb + cnt] = (uint16_t)id;
            }
        }
    }
}

// ---- K5: rank small buckets (1..64) — one wave per list entry (round-8 scheduling) ----
__global__ void __launch_bounds__(256) k_small(const ull* rec8, uint16_t* sid,
                                               const uint32_t* cnts, const ull* slist) {
    uint32_t gw   = (blockIdx.x * 256u + threadIdx.x) >> 6;
    uint32_t lane = threadIdx.x & 63u;
    uint32_t nw   = (gridDim.x * 256u) >> 6;
    uint32_t nsl  = cnts[1];
    for (uint32_t e = gw; e < nsl; e += nw) {
        ull ent = slist[e];
        uint32_t t     = (uint32_t)(ent >> 32);
        uint32_t start = (uint32_t)(ent >> 16) & 0xFFFFu;
        uint32_t m     = (uint32_t)ent & 0xFFFFu;
        size_t base = (size_t)t << 15;
        uint32_t id = 0xFFFFFFFFu, k = 0u;
        if (lane < m) {
            ull rr = rec8[base + start + lane];
            k = (uint32_t)(rr >> 32); id = (uint32_t)(rr & 0xFFFFu);
        }
        uint32_t cnt = 0;
        for (uint32_t q = 0; q < m; ++q) {
            uint32_t kq = __shfl(k, (int)q, 64);
            uint32_t iq = __shfl(id, (int)q, 64);
            cnt += (kq < k || (kq == k && iq < id)) ? 1u : 0u;
        }
        if (lane < m) sid[base + start + cnt] = (uint16_t)id;
    }
}

// ---- K6: per-row dot via LDS inverse permutation (round-8 verbatim) ----
__global__ void __launch_bounds__(1024) k_dot(const uint16_t* sid, double* rowloss) {
    extern __shared__ uint8_t smem[];
    uint16_t* inv = (uint16_t*)smem;    // 64 KB: inverse perm of targets row
    int r = blockIdx.x, tid = threadIdx.x;
    const uint4* t4 = (const uint4*)(sid + ((size_t)(r + N_ROWS) << 15));
    const uint4* p4 = (const uint4*)(sid + ((size_t)r << 15));
    for (int j8 = tid; j8 < N_COLS / 8; j8 += 1024) {
        uint4 v = t4[j8];
        uint32_t j = (uint32_t)j8 * 8u;
        inv[v.x & 0xFFFFu] = (uint16_t)(j + 0); inv[v.x >> 16] = (uint16_t)(j + 1);
        inv[v.y & 0xFFFFu] = (uint16_t)(j + 2); inv[v.y >> 16] = (uint16_t)(j + 3);
        inv[v.z & 0xFFFFu] = (uint16_t)(j + 4); inv[v.z >> 16] = (uint16_t)(j + 5);
        inv[v.w & 0xFFFFu] = (uint16_t)(j + 6); inv[v.w >> 16] = (uint16_t)(j + 7);
    }
    __syncthreads();
    ull s = 0;
    for (int j8 = tid; j8 < N_COLS / 8; j8 += 1024) {
        uint4 v = p4[j8];
        ull j = (ull)j8 * 8u;
        s += (j + 0) * (ull)inv[v.x & 0xFFFFu];
        s += (j + 1) * (ull)inv[v.x >> 16];
        s += (j + 2) * (ull)inv[v.y & 0xFFFFu];
        s += (j + 3) * (ull)inv[v.y >> 16];
        s += (j + 4) * (ull)inv[v.z & 0xFFFFu];
        s += (j + 5) * (ull)inv[v.z >> 16];
        s += (j + 6) * (ull)inv[v.w & 0xFFFFu];
        s += (j + 7) * (ull)inv[v.w >> 16];
    }
    for (int off = 32; off; off >>= 1) s += __shfl_down(s, off, 64);
    __shared__ ull sws[16];
    int w = tid >> 6, lane = tid & 63;
    if (lane == 0) sws[w] = s;
    __syncthreads();
    if (tid == 0) {
        ull tot = 0;
        for (int i = 0; i < 16; ++i) tot += sws[i];
        double S   = (double)tot;
        double num = S - 32768.0 * 16383.5 * 16383.5;        // S - n*mu^2 (exact)
        double den = 32768.0 * 1073741823.0 / 12.0;          // n(n^2-1)/12
        rowloss[r] = 1.0 - num / (den + 1e-8);
    }
}

// ---- K7: deterministic fixed-order final reduction ----
__global__ void __launch_bounds__(256) k_final(const double* rowloss, float* out) {
    __shared__ double s[256];
    s[threadIdx.x] = rowloss[threadIdx.x];
    __syncthreads();
    for (int off = 128; off; off >>= 1) {
        if ((int)threadIdx.x < off) s[threadIdx.x] += s[threadIdx.x + off];
        __syncthreads();
    }
    if (threadIdx.x == 0) out[0] = (float)(s[0] / 256.0);
}

extern "C" void kernel_launch(void* const* d_in, const int* in_sizes, int n_in,
                              void* d_out, int out_size, void* d_ws, size_t ws_size,
                              hipStream_t stream) {
    const float* P  = (const float*)d_in[0];
    const float* Tg = (const float*)d_in[1];
    float* out = (float*)d_out;
    char* ws = (char*)d_ws;
    const size_t MB = 1024 * 1024;

    uint32_t* hist = (uint32_t*)(ws);                          // 16 MB (512 x 8192 u32)
    uint32_t* cnts = (uint32_t*)(ws + 16 * MB);                // 16 B
    ull* list      = (ull*)(ws + 16 * MB + 4096);              // ~2 MB max
    ull* slist     = (ull*)(ws + 19 * MB);                     // 8 MB max
    uint16_t* sid  = (uint16_t*)(ws + 27 * MB);                // 32 MB
    double* rowloss = (double*)(ws + 59 * MB);                 // 2 KB
    ull* rec8      = (ull*)(ws + 60 * MB);                     // 128 MB -> total 188 MB (fits, r8 passed)

    (void)hipFuncSetAttribute((const void*)k_dot,
                              hipFuncAttributeMaxDynamicSharedMemorySize, 65536);

    hipMemsetAsync(cnts, 0, 16, stream);

    k_hist   <<<N_TASKS, 512, 0, stream>>>(P, Tg, hist);
    k_scan   <<<N_TASKS, 256, 0, stream>>>(hist, cnts, list, slist);
    k_scatter<<<N_TASKS, 512, 0, stream>>>(P, Tg, hist, rec8);
    k_large  <<<8192, 256, 0, stream>>>(rec8, sid, cnts, list);   // ~1 entry/wave; HW load-balances
    k_small  <<<4096, 256, 0, stream>>>(rec8, sid, cnts, slist);
    k_dot    <<<N_ROWS, 1024, 65536, stream>>>(sid, rowloss);
    k_final  <<<1, 256, 0, stream>>>(rowloss, out);
}